// Round 1
// baseline (214.411 us; speedup 1.0000x reference)
//
#include <hip/hip_runtime.h>

// Problem constants (reference: H=64, M=N=128, k=9, w=3)
constexpr int HZ = 64;
constexpr int NN = 128;
constexpr int P  = HZ * NN * NN;      // 1,048,576 voxels
constexpr int KSEL = 9;
constexpr int NCOL = 27;              // 3x3x3 window
constexpr int STRIDE = 12;            // padded row stride (16B-aligned float4/int4)

// ---------------------------------------------------------------------------
// Pass 1: per voxel, stable top-9 of the 27 neighbors by |v - center|.
// Rank method: rank[c] = #{c' : d[c'] < d[c]  or  (d[c']==d[c] and c' < c)}
// -> exact NumPy stable-argsort order. Fully unrolled, constant indices only
// (no scratch spills). Writes IDk (global flat index) and Wk (value) rows.
// ---------------------------------------------------------------------------
__global__ __launch_bounds__(256) void topk_kernel(
    const float* __restrict__ anat,
    int*   __restrict__ idk,
    float* __restrict__ wk) {
  const int i = blockIdx.x * 256 + threadIdx.x;   // grid sized exactly P
  const int x = i & (NN - 1);
  const int y = (i >> 7) & (NN - 1);
  const int z = i >> 14;

  float v[NCOL];
  #pragma unroll
  for (int c = 0; c < NCOL; ++c) {
    const int oz = c / 9 - 1, oy = (c / 3) % 3 - 1, ox = c % 3 - 1;
    const int zz = (z + oz) & (HZ - 1);
    const int yy = (y + oy) & (NN - 1);
    const int xx = (x + ox) & (NN - 1);
    v[c] = anat[(zz << 14) | (yy << 7) | xx];
  }
  const float center = v[13];   // oz=oy=ox=0 column

  float d[NCOL];
  #pragma unroll
  for (int c = 0; c < NCOL; ++c) d[c] = fabsf(v[c] - center);

  int r[NCOL];
  #pragma unroll
  for (int c = 0; c < NCOL; ++c) r[c] = 0;

  // 351 stable pairwise compares; a<b, tie -> a first (b's rank bumps).
  #pragma unroll
  for (int a = 0; a < NCOL; ++a) {
    #pragma unroll
    for (int b = a + 1; b < NCOL; ++b) {
      const bool le = (d[a] <= d[b]);
      r[b] += le ? 1 : 0;
      r[a] += le ? 0 : 1;
    }
  }

  #pragma unroll
  for (int c = 0; c < NCOL; ++c) {
    if (r[c] < KSEL) {
      const int oz = c / 9 - 1, oy = (c / 3) % 3 - 1, ox = c % 3 - 1;
      const int zz = (z + oz) & (HZ - 1);
      const int yy = (y + oy) & (NN - 1);
      const int xx = (x + ox) & (NN - 1);
      const int nidx = (zz << 14) | (yy << 7) | xx;
      idk[i * STRIDE + r[c]] = nidx;
      wk [i * STRIDE + r[c]] = v[c];
    }
  }
}

// ---------------------------------------------------------------------------
// Pass 2: per voxel, sigma (ddof=1) of own Wk row; for each of 9 selected
// neighbors, patch distance vs that neighbor's Wk row; softmax over 9.
// logits = -sumsq / (2*ks^2*sigma^2)  (== -(sqrt(sumsq)/sigma/(sqrt2*ks))^2)
// ---------------------------------------------------------------------------
__global__ __launch_bounds__(256) void weights_kernel(
    const float* __restrict__ wk,
    const int*   __restrict__ idk,
    const float* __restrict__ ksig,
    float* __restrict__ out) {
  const int i = blockIdx.x * 256 + threadIdx.x;

  const float4* wrow = (const float4*)(wk + (size_t)i * STRIDE);
  const float4 w0 = wrow[0], w1 = wrow[1], w2 = wrow[2];
  const float ws[KSEL] = {w0.x, w0.y, w0.z, w0.w, w1.x, w1.y, w1.z, w1.w, w2.x};

  const int4* irow = (const int4*)(idk + (size_t)i * STRIDE);
  const int4 i0 = irow[0], i1 = irow[1], i2 = irow[2];
  const int nb[KSEL] = {i0.x, i0.y, i0.z, i0.w, i1.x, i1.y, i1.z, i1.w, i2.x};

  // sigma with ddof=1 (two-pass, matches jnp.std)
  float mean = 0.f;
  #pragma unroll
  for (int l = 0; l < KSEL; ++l) mean += ws[l];
  mean *= (1.0f / 9.0f);
  float var = 0.f;
  #pragma unroll
  for (int l = 0; l < KSEL; ++l) { const float t = ws[l] - mean; var += t * t; }
  var *= (1.0f / 8.0f);
  const float sigma = sqrtf(var);

  const float ks = ksig[0];
  // sigma==0 -> logits forced to 0 (reference where()); else scale factor.
  const float inv = (sigma == 0.f) ? 0.f : 1.0f / (2.0f * ks * ks * sigma * sigma);

  float logit[KSEL];
  #pragma unroll
  for (int j = 0; j < KSEL; ++j) {
    const float4* nrow = (const float4*)(wk + (size_t)nb[j] * STRIDE);
    const float4 n0 = nrow[0], n1 = nrow[1], n2 = nrow[2];
    const float nv[KSEL] = {n0.x, n0.y, n0.z, n0.w, n1.x, n1.y, n1.z, n1.w, n2.x};
    float s = 0.f;
    #pragma unroll
    for (int l = 0; l < KSEL; ++l) {
      const float t = ws[l] - nv[l] + 1e-6f;
      s = fmaf(t, t, s);
    }
    logit[j] = -s * inv;
  }

  // softmax over the 9 logits
  float mx = logit[0];
  #pragma unroll
  for (int j = 1; j < KSEL; ++j) mx = fmaxf(mx, logit[j]);
  float sum = 0.f;
  float e[KSEL];
  #pragma unroll
  for (int j = 0; j < KSEL; ++j) { e[j] = __expf(logit[j] - mx); sum += e[j]; }
  const float rs = 1.0f / sum;
  #pragma unroll
  for (int j = 0; j < KSEL; ++j) out[(size_t)i * KSEL + j] = e[j] * rs;
}

// ---------------------------------------------------------------------------
// d_in: [0] input (P floats), [1] ksigma (1 float), [2] k (int), [3] w (int)
// d_ws layout: Wk rows (P*STRIDE floats = 48 MB) | IDk rows (P*STRIDE ints = 48 MB)
// ---------------------------------------------------------------------------
extern "C" void kernel_launch(void* const* d_in, const int* in_sizes, int n_in,
                              void* d_out, int out_size, void* d_ws, size_t ws_size,
                              hipStream_t stream) {
  const float* anat = (const float*)d_in[0];
  const float* ksig = (const float*)d_in[1];

  float* wk  = (float*)d_ws;
  int*   idk = (int*)((char*)d_ws + (size_t)P * STRIDE * sizeof(float));

  const int blocks = P / 256;
  topk_kernel<<<blocks, 256, 0, stream>>>(anat, idk, wk);
  weights_kernel<<<blocks, 256, 0, stream>>>(wk, idk, ksig, (float*)d_out);
}

// Round 2
// 167.227 us; speedup vs baseline: 1.2822x; 1.2822x over previous
//
#include <hip/hip_runtime.h>

// Problem constants (reference: H=64, M=N=128, k=9, w=3)
constexpr int HZ   = 64;
constexpr int NN   = 128;
constexpr int P    = HZ * NN * NN;    // 1,048,576 voxels
constexpr int KSEL = 9;
constexpr int NCOL = 27;              // 3x3x3 window
constexpr int ST   = 12;              // row stride in floats (48 B, float4-aligned)
// Row layout (12 floats): [0..8] sorted top-9 values, [9] code_lo (6x5b),
// [10] code_hi (3x5b), [11] pad/garbage.

// ---------------------------------------------------------------------------
// Pass 1: stable top-9 of 27 neighbors by |v - center|.
// Ranks via 351 pairwise u32-bit compares (d>=0 so float bits are order-
// preserving; le + (a<b) ordering reproduces NumPy stable ties).
// 3 VALU/pair: v_cmp_le_u32 + addc + subb with r[a] preinit 26-a.
// Values scattered into an LDS row, IDs packed as 5-bit column codes, then
// fully-coalesced float4 writeback (fixes the 300+_MB RMW write amplification).
// ---------------------------------------------------------------------------
__global__ __launch_bounds__(256) void topk2(
    const float* __restrict__ anat,
    float* __restrict__ rows) {
  __shared__ float lds[256 * ST];   // 12 KB
  const int tid = threadIdx.x;
  const int i = blockIdx.x * 256 + tid;
  const int x = i & (NN - 1);
  const int y = (i >> 7) & (NN - 1);
  const int z = i >> 14;

  float v[NCOL];
  #pragma unroll
  for (int c = 0; c < NCOL; ++c) {
    const int oz = c / 9 - 1, oy = (c / 3) % 3 - 1, ox = c % 3 - 1;
    const int zz = (z + oz) & (HZ - 1);
    const int yy = (y + oy) & (NN - 1);
    const int xx = (x + ox) & (NN - 1);
    v[c] = anat[(zz << 14) | (yy << 7) | xx];
  }
  const float center = v[13];

  unsigned kb[NCOL];
  #pragma unroll
  for (int c = 0; c < NCOL; ++c) kb[c] = __float_as_uint(fabsf(v[c] - center));

  // r[c] = stable rank. Init 26-c; per pair (a<b): x=[kb[a]<=kb[b]] -> r[b]+=x, r[a]-=x.
  int r[NCOL];
  #pragma unroll
  for (int c = 0; c < NCOL; ++c) r[c] = (NCOL - 1) - c;
  #pragma unroll
  for (int a = 0; a < NCOL; ++a) {
    #pragma unroll
    for (int b = a + 1; b < NCOL; ++b) {
      const int xle = (kb[a] <= kb[b]) ? 1 : 0;
      r[b] += xle;
      r[a] -= xle;
    }
  }

  // Scatter values into own LDS row; ranks >=9 dump into pad slot 11
  // (slots 9/10 are written AFTER with the codes, so dumps must avoid them).
  float* myrow = &lds[tid * ST];
  #pragma unroll
  for (int c = 0; c < NCOL; ++c) {
    const int slot = (r[c] < KSEL) ? r[c] : 11;
    myrow[slot] = v[c];
  }

  // Pack the 9 winning column codes (5 bits each) by rank position.
  unsigned lo = 0, hi = 0;
  #pragma unroll
  for (int c = 0; c < NCOL; ++c) {
    const unsigned rr = (unsigned)r[c];
    const unsigned sh = rr * 5u;
    const unsigned contrib = (unsigned)c << (sh >= 30u ? sh - 30u : sh);
    if (rr < 6u) lo |= contrib;
    else if (rr < 9u) hi |= contrib;
  }
  myrow[9]  = __uint_as_float(lo);
  myrow[10] = __uint_as_float(hi);

  __syncthreads();

  // Coalesced writeback: 3 rounds x 256 lanes x float4 = 12 KB (full coverage,
  // every line fully dirty -> no read-modify-write).
  float4* g = (float4*)(rows + (size_t)blockIdx.x * 256 * ST);
  const float4* l4 = (const float4*)lds;
  #pragma unroll
  for (int rnd = 0; rnd < 3; ++rnd) g[rnd * 256 + tid] = l4[rnd * 256 + tid];
}

// ---------------------------------------------------------------------------
// Pass 2: sigma (ddof=1) of own row, gather 9 neighbor rows (decoded from the
// packed codes), patch-distance logits, softmax, LDS-staged coalesced output.
// logits = -sumsq / (2*ks^2*var)  ==  -(sqrt(sumsq)/sigma/(sqrt2*ks))^2
// ---------------------------------------------------------------------------
__global__ __launch_bounds__(256) void weights2(
    const float* __restrict__ rows,
    const float* __restrict__ ksig,
    float* __restrict__ out) {
  __shared__ float lds[256 * KSEL];   // 9 KB
  const int tid = threadIdx.x;
  const int i = blockIdx.x * 256 + tid;
  const int x = i & (NN - 1);
  const int y = (i >> 7) & (NN - 1);
  const int z = i >> 14;

  const float4* wrow = (const float4*)(rows + (size_t)i * ST);
  const float4 w0 = wrow[0], w1 = wrow[1], w2 = wrow[2];
  const float ws[KSEL] = {w0.x, w0.y, w0.z, w0.w, w1.x, w1.y, w1.z, w1.w, w2.x};
  const unsigned lo = __float_as_uint(w2.y);
  const unsigned hi = __float_as_uint(w2.z);

  // sigma with ddof=1 (two-pass, matches jnp.std)
  float mean = 0.f;
  #pragma unroll
  for (int l = 0; l < KSEL; ++l) mean += ws[l];
  mean *= (1.0f / 9.0f);
  float var = 0.f;
  #pragma unroll
  for (int l = 0; l < KSEL; ++l) { const float t = ws[l] - mean; var += t * t; }
  var *= (1.0f / 8.0f);
  const float sigma = sqrtf(var);

  const float ks = ksig[0];
  const float inv = (sigma == 0.f) ? 0.f : 1.0f / (2.0f * ks * ks * sigma * sigma);

  float logit[KSEL];
  #pragma unroll
  for (int j = 0; j < KSEL; ++j) {
    // decode 5-bit column code -> (oz,oy,ox) -> neighbor flat index
    const unsigned c = (j < 6) ? ((lo >> (5 * j)) & 31u)
                               : ((hi >> (5 * (j - 6))) & 31u);
    const unsigned czi = (c * 57u) >> 9;          // c / 9  (exact for c < 32)
    const unsigned rem = c - 9u * czi;
    const unsigned cyi = (rem * 11u) >> 5;        // rem / 3 (exact for rem < 9)
    const unsigned cxi = rem - 3u * cyi;
    const int zz = (z + (int)czi - 1) & (HZ - 1);
    const int yy = (y + (int)cyi - 1) & (NN - 1);
    const int xx = (x + (int)cxi - 1) & (NN - 1);
    const int nidx = (zz << 14) | (yy << 7) | xx;

    const float4* nrow = (const float4*)(rows + (size_t)nidx * ST);
    const float4 n0 = nrow[0], n1 = nrow[1], n2 = nrow[2];
    const float nv[KSEL] = {n0.x, n0.y, n0.z, n0.w, n1.x, n1.y, n1.z, n1.w, n2.x};
    float s = 0.f;
    #pragma unroll
    for (int l = 0; l < KSEL; ++l) {
      const float t = ws[l] - nv[l] + 1e-6f;
      s = fmaf(t, t, s);
    }
    logit[j] = -s * inv;
  }

  // softmax over the 9 logits
  float mx = logit[0];
  #pragma unroll
  for (int j = 1; j < KSEL; ++j) mx = fmaxf(mx, logit[j]);
  float sum = 0.f;
  float e[KSEL];
  #pragma unroll
  for (int j = 0; j < KSEL; ++j) { e[j] = __expf(logit[j] - mx); sum += e[j]; }
  const float rs = 1.0f / sum;

  // Stage through LDS (stride 9 is odd*9 -> conflict-free scatter) then
  // fully-coalesced float4 stores: 2304 floats = 576 float4 per block.
  #pragma unroll
  for (int j = 0; j < KSEL; ++j) lds[tid * KSEL + j] = e[j] * rs;
  __syncthreads();

  const float4* l4 = (const float4*)lds;
  float4* g = (float4*)(out + (size_t)blockIdx.x * (256 * KSEL));
  g[tid]       = l4[tid];
  g[256 + tid] = l4[256 + tid];
  if (tid < 64) g[512 + tid] = l4[512 + tid];
}

// ---------------------------------------------------------------------------
// d_in: [0] input (P floats), [1] ksigma (1 float), [2] k (int), [3] w (int)
// d_ws: row array, P * 12 floats = 48 MB
// ---------------------------------------------------------------------------
extern "C" void kernel_launch(void* const* d_in, const int* in_sizes, int n_in,
                              void* d_out, int out_size, void* d_ws, size_t ws_size,
                              hipStream_t stream) {
  const float* anat = (const float*)d_in[0];
  const float* ksig = (const float*)d_in[1];
  float* rows = (float*)d_ws;

  const int blocks = P / 256;
  topk2<<<blocks, 256, 0, stream>>>(anat, rows);
  weights2<<<blocks, 256, 0, stream>>>(rows, ksig, (float*)d_out);
}

// Round 3
// 160.566 us; speedup vs baseline: 1.3353x; 1.0415x over previous
//
#include <hip/hip_runtime.h>

// Problem constants (reference: H=64, M=N=128, k=9, w=3)
constexpr int HZ   = 64;
constexpr int NN   = 128;
constexpr int P    = HZ * NN * NN;    // 1,048,576 voxels
constexpr int KSEL = 9;
constexpr int NCOL = 27;              // 3x3x3 window
constexpr int ST   = 12;              // row stride in floats (48 B, float4-aligned)
// Row layout (12 floats): [0..8] sorted top-9 values, [9] code_lo (6x5b),
// [10] code_hi (3x5b), [11] pad/garbage.

// ---------------------------------------------------------------------------
// Pass 1: stable top-9 of 27 neighbors by |v - center|.
// Gather through a 6 KB LDS halo tile (3z x 4y x 128x) staged with coalesced
// float4 loads -> per-thread reads are conflict-free ds_read_b32 (x-wrap via
// mask), removing ~200 VALU ops/thread of global address arithmetic.
// Ranks via 351 stable pairwise u32-bit compares (d>=0 so float bits are
// order-preserving); LDS-row scatter + packed 5-bit codes + coalesced
// float4 writeback (R2's fix for write amplification).
// ---------------------------------------------------------------------------
__global__ __launch_bounds__(256) void topk3(
    const float* __restrict__ anat,
    float* __restrict__ rows) {
  __shared__ float tile[12 * 128];   // 6 KB: [zi 0..2][yrow 0..3][x 0..127]
  __shared__ float lrow[256 * ST];   // 12 KB output staging
  const int tid = threadIdx.x;
  const int ib  = blockIdx.x << 8;   // first voxel of block
  const int x   = tid & (NN - 1);
  const int yl  = tid >> 7;          // 0/1: thread's y within block
  const int y0  = (ib >> 7) & (NN - 1);
  const int z   = ib >> 14;

  // Stage halo: 12 rows x 32 float4 = 384 float4.
  #pragma unroll
  for (int s = 0; s < 2; ++s) {
    const int q = tid + s * 256;
    if (q < 384) {
      const int row = q >> 5;        // 0..11 = zi*4 + yrow
      const int col = q & 31;
      const int zz = (z + (row >> 2) - 1) & (HZ - 1);
      const int yy = (y0 + (row & 3) - 1) & (NN - 1);
      ((float4*)tile)[q] =
          *(const float4*)(anat + ((zz << 14) | (yy << 7) | (col << 2)));
    }
  }
  __syncthreads();

  const int xa[3] = {(x + NN - 1) & (NN - 1), x, (x + 1) & (NN - 1)};

  float v[NCOL];
  #pragma unroll
  for (int c = 0; c < NCOL; ++c) {
    const int zi = c / 9, yi = (c / 3) % 3;
    v[c] = tile[zi * 512 + (yl + yi) * 128 + xa[c % 3]];
  }
  const float center = v[13];

  unsigned kb[NCOL];
  #pragma unroll
  for (int c = 0; c < NCOL; ++c) kb[c] = __float_as_uint(fabsf(v[c] - center));

  // r[c] = stable rank. Init 26-c; per pair (a<b): x=[kb[a]<=kb[b]] -> r[b]+=x, r[a]-=x.
  int r[NCOL];
  #pragma unroll
  for (int c = 0; c < NCOL; ++c) r[c] = (NCOL - 1) - c;
  #pragma unroll
  for (int a = 0; a < NCOL; ++a) {
    #pragma unroll
    for (int b = a + 1; b < NCOL; ++b) {
      const int xle = (kb[a] <= kb[b]) ? 1 : 0;
      r[b] += xle;
      r[a] -= xle;
    }
  }

  // Scatter values into own LDS row; ranks >=9 dump into pad slot 11.
  float* myrow = &lrow[tid * ST];
  #pragma unroll
  for (int c = 0; c < NCOL; ++c) {
    const int slot = (r[c] < KSEL) ? r[c] : 11;
    myrow[slot] = v[c];
  }

  // Pack the 9 winning column codes (5 bits each) by rank position.
  unsigned lo = 0, hi = 0;
  #pragma unroll
  for (int c = 0; c < NCOL; ++c) {
    const unsigned rr = (unsigned)r[c];
    const unsigned sh = rr * 5u;
    const unsigned contrib = (unsigned)c << (sh >= 30u ? sh - 30u : sh);
    if (rr < 6u) lo |= contrib;
    else if (rr < 9u) hi |= contrib;
  }
  myrow[9]  = __uint_as_float(lo);
  myrow[10] = __uint_as_float(hi);

  __syncthreads();

  // Coalesced writeback: 3 x 256 x float4 = 12 KB, full line coverage.
  float4* g = (float4*)(rows + (size_t)blockIdx.x * 256 * ST);
  const float4* l4 = (const float4*)lrow;
  #pragma unroll
  for (int rnd = 0; rnd < 3; ++rnd) g[rnd * 256 + tid] = l4[rnd * 256 + tid];
}

// ---------------------------------------------------------------------------
// Pass 2: decode all 9 neighbor ids, issue ALL 27 float4 gathers into
// registers up front (fixes R2's VGPR=32 serialization -> 27 loads in
// flight/wave), then sigma (ddof=1), patch-distance logits, softmax,
// LDS-staged coalesced output.
// logits = -sumsq / (2*ks^2*var)  ==  -(sqrt(sumsq)/sigma/(sqrt2*ks))^2
// ---------------------------------------------------------------------------
__global__ __launch_bounds__(256, 3) void weights3(
    const float* __restrict__ rows,
    const float* __restrict__ ksig,
    float* __restrict__ out) {
  __shared__ float lds[256 * KSEL];   // 9 KB
  const int tid = threadIdx.x;
  const int i = blockIdx.x * 256 + tid;
  const int x = i & (NN - 1);
  const int y = (i >> 7) & (NN - 1);
  const int z = i >> 14;

  const float4* wrow = (const float4*)(rows + (size_t)i * ST);
  const float4 w0 = wrow[0], w1 = wrow[1], w2 = wrow[2];
  const float ws[KSEL] = {w0.x, w0.y, w0.z, w0.w, w1.x, w1.y, w1.z, w1.w, w2.x};
  const unsigned lo = __float_as_uint(w2.y);
  const unsigned hi = __float_as_uint(w2.z);

  // Decode all 9 neighbor flat indices.
  int nidx[KSEL];
  #pragma unroll
  for (int j = 0; j < KSEL; ++j) {
    const unsigned c = (j < 6) ? ((lo >> (5 * j)) & 31u)
                               : ((hi >> (5 * (j - 6))) & 31u);
    const unsigned czi = (c * 57u) >> 9;          // c / 9  (exact for c < 32)
    const unsigned rem = c - 9u * czi;
    const unsigned cyi = (rem * 11u) >> 5;        // rem / 3 (exact for rem < 9)
    const unsigned cxi = rem - 3u * cyi;
    const int zz = (z + (int)czi - 1) & (HZ - 1);
    const int yy = (y + (int)cyi - 1) & (NN - 1);
    const int xx = (x + (int)cxi - 1) & (NN - 1);
    nidx[j] = (zz << 14) | (yy << 7) | xx;
  }

  // Issue all 27 gather loads (independent -> all in flight).
  float4 buf[KSEL][3];
  #pragma unroll
  for (int j = 0; j < KSEL; ++j) {
    const float4* nrow = (const float4*)(rows + (size_t)nidx[j] * ST);
    buf[j][0] = nrow[0];
    buf[j][1] = nrow[1];
    buf[j][2] = nrow[2];
  }

  // sigma with ddof=1 (two-pass, matches jnp.std)
  float mean = 0.f;
  #pragma unroll
  for (int l = 0; l < KSEL; ++l) mean += ws[l];
  mean *= (1.0f / 9.0f);
  float var = 0.f;
  #pragma unroll
  for (int l = 0; l < KSEL; ++l) { const float t = ws[l] - mean; var += t * t; }
  var *= (1.0f / 8.0f);
  const float sigma = sqrtf(var);

  const float ks = ksig[0];
  const float inv = (sigma == 0.f) ? 0.f : 1.0f / (2.0f * ks * ks * sigma * sigma);

  float logit[KSEL];
  #pragma unroll
  for (int j = 0; j < KSEL; ++j) {
    const float nv[KSEL] = {buf[j][0].x, buf[j][0].y, buf[j][0].z, buf[j][0].w,
                            buf[j][1].x, buf[j][1].y, buf[j][1].z, buf[j][1].w,
                            buf[j][2].x};
    float s = 0.f;
    #pragma unroll
    for (int l = 0; l < KSEL; ++l) {
      const float t = ws[l] - nv[l] + 1e-6f;
      s = fmaf(t, t, s);
    }
    logit[j] = -s * inv;
  }

  // softmax over the 9 logits
  float mx = logit[0];
  #pragma unroll
  for (int j = 1; j < KSEL; ++j) mx = fmaxf(mx, logit[j]);
  float sum = 0.f;
  float e[KSEL];
  #pragma unroll
  for (int j = 0; j < KSEL; ++j) { e[j] = __expf(logit[j] - mx); sum += e[j]; }
  const float rs = 1.0f / sum;

  // Stage through LDS then fully-coalesced float4 stores.
  #pragma unroll
  for (int j = 0; j < KSEL; ++j) lds[tid * KSEL + j] = e[j] * rs;
  __syncthreads();

  const float4* l4 = (const float4*)lds;
  float4* g = (float4*)(out + (size_t)blockIdx.x * (256 * KSEL));
  g[tid]       = l4[tid];
  g[256 + tid] = l4[256 + tid];
  if (tid < 64) g[512 + tid] = l4[512 + tid];
}

// ---------------------------------------------------------------------------
// d_in: [0] input (P floats), [1] ksigma (1 float), [2] k (int), [3] w (int)
// d_ws: row array, P * 12 floats = 48 MB
// ---------------------------------------------------------------------------
extern "C" void kernel_launch(void* const* d_in, const int* in_sizes, int n_in,
                              void* d_out, int out_size, void* d_ws, size_t ws_size,
                              hipStream_t stream) {
  const float* anat = (const float*)d_in[0];
  const float* ksig = (const float*)d_in[1];
  float* rows = (float*)d_ws;

  const int blocks = P / 256;
  topk3<<<blocks, 256, 0, stream>>>(anat, rows);
  weights3<<<blocks, 256, 0, stream>>>(rows, ksig, (float*)d_out);
}

// Round 4
// 151.374 us; speedup vs baseline: 1.4164x; 1.0607x over previous
//
#include <hip/hip_runtime.h>

// Problem constants (reference: H=64, M=N=128, k=9, w=3)
constexpr int HZ   = 64;
constexpr int NN   = 128;
constexpr int P    = HZ * NN * NN;    // 1,048,576 voxels
constexpr int KSEL = 9;
constexpr int NCOL = 27;              // 3x3x3 window
constexpr int ST   = 12;              // row stride in floats (48 B, float4-aligned)
// Row layout (12 floats): [0..8] sorted top-9 values, [9] code_lo (6x5b),
// [10] code_hi (3x5b), [11] pad/garbage.

// ---------------------------------------------------------------------------
// Pass 1: stable top-9 of 27 neighbors by |v - center| (unchanged from R3).
// ---------------------------------------------------------------------------
__global__ __launch_bounds__(256) void topk3(
    const float* __restrict__ anat,
    float* __restrict__ rows) {
  __shared__ float tile[12 * 128];   // 6 KB: [zi 0..2][yrow 0..3][x 0..127]
  __shared__ float lrow[256 * ST];   // 12 KB output staging
  const int tid = threadIdx.x;
  const int ib  = blockIdx.x << 8;
  const int x   = tid & (NN - 1);
  const int yl  = tid >> 7;
  const int y0  = (ib >> 7) & (NN - 1);
  const int z   = ib >> 14;

  #pragma unroll
  for (int s = 0; s < 2; ++s) {
    const int q = tid + s * 256;
    if (q < 384) {
      const int row = q >> 5;
      const int col = q & 31;
      const int zz = (z + (row >> 2) - 1) & (HZ - 1);
      const int yy = (y0 + (row & 3) - 1) & (NN - 1);
      ((float4*)tile)[q] =
          *(const float4*)(anat + ((zz << 14) | (yy << 7) | (col << 2)));
    }
  }
  __syncthreads();

  const int xa[3] = {(x + NN - 1) & (NN - 1), x, (x + 1) & (NN - 1)};

  float v[NCOL];
  #pragma unroll
  for (int c = 0; c < NCOL; ++c) {
    const int zi = c / 9, yi = (c / 3) % 3;
    v[c] = tile[zi * 512 + (yl + yi) * 128 + xa[c % 3]];
  }
  const float center = v[13];

  unsigned kb[NCOL];
  #pragma unroll
  for (int c = 0; c < NCOL; ++c) kb[c] = __float_as_uint(fabsf(v[c] - center));

  int r[NCOL];
  #pragma unroll
  for (int c = 0; c < NCOL; ++c) r[c] = (NCOL - 1) - c;
  #pragma unroll
  for (int a = 0; a < NCOL; ++a) {
    #pragma unroll
    for (int b = a + 1; b < NCOL; ++b) {
      const int xle = (kb[a] <= kb[b]) ? 1 : 0;
      r[b] += xle;
      r[a] -= xle;
    }
  }

  float* myrow = &lrow[tid * ST];
  #pragma unroll
  for (int c = 0; c < NCOL; ++c) {
    const int slot = (r[c] < KSEL) ? r[c] : 11;
    myrow[slot] = v[c];
  }

  unsigned lo = 0, hi = 0;
  #pragma unroll
  for (int c = 0; c < NCOL; ++c) {
    const unsigned rr = (unsigned)r[c];
    const unsigned sh = rr * 5u;
    const unsigned contrib = (unsigned)c << (sh >= 30u ? sh - 30u : sh);
    if (rr < 6u) lo |= contrib;
    else if (rr < 9u) hi |= contrib;
  }
  myrow[9]  = __uint_as_float(lo);
  myrow[10] = __uint_as_float(hi);

  __syncthreads();

  float4* g = (float4*)(rows + (size_t)blockIdx.x * 256 * ST);
  const float4* l4 = (const float4*)lrow;
  #pragma unroll
  for (int rnd = 0; rnd < 3; ++rnd) g[rnd * 256 + tid] = l4[rnd * 256 + tid];
}

// ---------------------------------------------------------------------------
// Pass 2 (R4): stage the whole 3z x 4y x 128x halo of rows (1536 rows,
// 73.7 KB) into LDS with coalesced float4 loads, then every neighbor gather
// is a conflict-free ds_read_b128 (row stride 12 words: 8 consecutive rows
// cover all 32 banks exactly once). XCD swizzle keeps the 6x halo re-read in
// the local L2. Fixes R3's scattered-load latency wall (VALUBusy 24%).
// ---------------------------------------------------------------------------
__global__ __launch_bounds__(256) void weights4(
    const float* __restrict__ rows,
    const float* __restrict__ ksig,
    float* __restrict__ out) {
  __shared__ float tile[1536 * ST];   // 73728 B; reused for output staging
  const int tid = threadIdx.x;

  // XCD-aware swizzle: 4096 blocks = 8 XCDs x 512. Round-robin dispatch ->
  // XCD k executes contiguous slab [k*512, (k+1)*512): z-slab of 8, L2-local.
  const int blk = blockIdx.x;
  const int swz = ((blk & 7) << 9) | (blk >> 3);

  const int ib = swz << 8;
  const int x  = tid & (NN - 1);
  const int yl = tid >> 7;
  const int y0 = (ib >> 7) & (NN - 1);
  const int z  = ib >> 14;

  // ---- Stage halo: 12 (zi,yi) pairs x 384 float4 = 4608 float4. ----
  const float4* rows4 = (const float4*)rows;
  float4* t4 = (float4*)tile;
  #pragma unroll
  for (int s = 0; s < 18; ++s) {
    const unsigned q = (unsigned)(s * 256 + tid);
    const unsigned p = q / 384u;          // (zi,yi) pair 0..11
    const unsigned f = q - p * 384u;      // float4 within the 128-row run
    const int zi = (int)(p >> 2), yi = (int)(p & 3u);
    const int zz = (z + zi - 1) & (HZ - 1);
    const int yy = (y0 + yi - 1) & (NN - 1);
    const int g0 = (zz << 14) | (yy << 7);   // voxel id at x=0
    t4[q] = rows4[(size_t)g0 * 3 + f];
  }
  __syncthreads();

  // ---- Own row (zi=1, yi=yl+1). ----
  const int rho_own = 512 + (yl + 1) * 128 + x;
  const float4 w0 = t4[rho_own * 3], w1 = t4[rho_own * 3 + 1], w2 = t4[rho_own * 3 + 2];
  const float ws[KSEL] = {w0.x, w0.y, w0.z, w0.w, w1.x, w1.y, w1.z, w1.w, w2.x};
  const unsigned lo = __float_as_uint(w2.y);
  const unsigned hi = __float_as_uint(w2.z);

  // sigma with ddof=1 (two-pass, matches jnp.std)
  float mean = 0.f;
  #pragma unroll
  for (int l = 0; l < KSEL; ++l) mean += ws[l];
  mean *= (1.0f / 9.0f);
  float var = 0.f;
  #pragma unroll
  for (int l = 0; l < KSEL; ++l) { const float t = ws[l] - mean; var += t * t; }
  var *= (1.0f / 8.0f);
  const float sigma = sqrtf(var);

  const float ks = ksig[0];
  const float inv = (sigma == 0.f) ? 0.f : 1.0f / (2.0f * ks * ks * sigma * sigma);

  float logit[KSEL];
  #pragma unroll
  for (int j = 0; j < KSEL; ++j) {
    const unsigned c = (j < 6) ? ((lo >> (5 * j)) & 31u)
                               : ((hi >> (5 * (j - 6))) & 31u);
    const unsigned czi = (c * 57u) >> 9;          // c / 9
    const unsigned rem = c - 9u * czi;
    const unsigned cyi = (rem * 11u) >> 5;        // rem / 3
    const unsigned cxi = rem - 3u * cyi;
    // tile row of that neighbor: zi = czi, yi = yl + cyi, x wraps in-tile
    const int rho = (int)czi * 512 + (yl + (int)cyi) * 128 + ((x + (int)cxi - 1) & (NN - 1));
    const float4 n0 = t4[rho * 3], n1 = t4[rho * 3 + 1], n2 = t4[rho * 3 + 2];
    const float nv[KSEL] = {n0.x, n0.y, n0.z, n0.w, n1.x, n1.y, n1.z, n1.w, n2.x};
    float s = 0.f;
    #pragma unroll
    for (int l = 0; l < KSEL; ++l) {
      const float t = ws[l] - nv[l] + 1e-6f;
      s = fmaf(t, t, s);
    }
    logit[j] = -s * inv;
  }

  // softmax over the 9 logits
  float mx = logit[0];
  #pragma unroll
  for (int j = 1; j < KSEL; ++j) mx = fmaxf(mx, logit[j]);
  float sum = 0.f;
  float e[KSEL];
  #pragma unroll
  for (int j = 0; j < KSEL; ++j) { e[j] = __expf(logit[j] - mx); sum += e[j]; }
  const float rs = 1.0f / sum;

  // ---- Reuse tile front as output staging (all tile reads are done). ----
  __syncthreads();
  #pragma unroll
  for (int j = 0; j < KSEL; ++j) tile[tid * KSEL + j] = e[j] * rs;
  __syncthreads();

  float4* g = (float4*)(out + (size_t)swz * (256 * KSEL));
  g[tid]       = t4[tid];
  g[256 + tid] = t4[256 + tid];
  if (tid < 64) g[512 + tid] = t4[512 + tid];
}

// ---------------------------------------------------------------------------
// d_in: [0] input (P floats), [1] ksigma (1 float), [2] k (int), [3] w (int)
// d_ws: row array, P * 12 floats = 48 MB
// ---------------------------------------------------------------------------
extern "C" void kernel_launch(void* const* d_in, const int* in_sizes, int n_in,
                              void* d_out, int out_size, void* d_ws, size_t ws_size,
                              hipStream_t stream) {
  const float* anat = (const float*)d_in[0];
  const float* ksig = (const float*)d_in[1];
  float* rows = (float*)d_ws;

  const int blocks = P / 256;
  topk3<<<blocks, 256, 0, stream>>>(anat, rows);
  weights4<<<blocks, 256, 0, stream>>>(rows, ksig, (float*)d_out);
}

// Round 5
// 140.792 us; speedup vs baseline: 1.5229x; 1.0752x over previous
//
#include <hip/hip_runtime.h>
#include <array>

// Problem constants (reference: H=64, M=N=128, k=9, w=3)
constexpr int HZ   = 64;
constexpr int NN   = 128;
constexpr int P    = HZ * NN * NN;    // 1,048,576 voxels
constexpr int KSEL = 9;
constexpr int NCOL = 27;              // 3x3x3 window
constexpr int ST   = 12;              // row stride in floats (48 B, float4-aligned)
// Row layout (12 floats): [0..8] sorted top-9 values, [9] code_lo (6x5b),
// [10] code_hi (3x5b), [11] pad/garbage.

// ---------------------------------------------------------------------------
// Batcher merge-exchange network for n=27 (Knuth 5.2.2M — valid for any n).
// 155 compare-exchanges, constexpr-generated so the unrolled loop has
// compile-time indices (register-resident array, no spills).
// ---------------------------------------------------------------------------
constexpr int compute_nce(int n) {
  int t = 0; while ((1 << t) < n) ++t;
  int cnt = 0;
  for (int p = 1 << (t - 1); p > 0; p >>= 1) {
    int q = 1 << (t - 1), r = 0, d = p;
    while (true) {
      for (int i = 0; i < n - d; ++i)
        if ((i & p) == r) ++cnt;
      if (q == p) break;
      d = q - p; r = p; q >>= 1;
    }
  }
  return cnt;
}
constexpr int NCE = compute_nce(NCOL);   // 155

struct CEPair { unsigned char a, b; };
constexpr std::array<CEPair, NCE> make_net() {
  std::array<CEPair, NCE> net{};
  int t = 0; while ((1 << t) < NCOL) ++t;
  int k = 0;
  for (int p = 1 << (t - 1); p > 0; p >>= 1) {
    int q = 1 << (t - 1), r = 0, d = p;
    while (true) {
      for (int i = 0; i < NCOL - d; ++i)
        if ((i & p) == r) {
          net[k].a = (unsigned char)i;
          net[k].b = (unsigned char)(i + d);
          ++k;
        }
      if (q == p) break;
      d = q - p; r = p; q >>= 1;
    }
  }
  return net;
}
constexpr auto NET = make_net();

// ---------------------------------------------------------------------------
// Pass 1 (R5): stable top-9 of 27 neighbors by |v - center| via a sorting
// network on u64 keys (distbits<<5 | col). Ties strict via col LSBs -> exact
// NumPy stable order. Winners exit in rank order: sequential LDS-row writes
// (no rank scatter) + direct code packing. ~1000 VALU/thread vs R4's ~1400.
// ---------------------------------------------------------------------------
__global__ __launch_bounds__(256) void topk4(
    const float* __restrict__ anat,
    float* __restrict__ rows) {
  __shared__ float tile[12 * 128];   // 6 KB: [zi 0..2][yrow 0..3][x 0..127]
  __shared__ float lrow[256 * ST];   // 12 KB output staging
  const int tid = threadIdx.x;
  const int ib  = blockIdx.x << 8;
  const int x   = tid & (NN - 1);
  const int yl  = tid >> 7;
  const int y0  = (ib >> 7) & (NN - 1);
  const int z   = ib >> 14;

  // Stage halo: 12 rows x 32 float4 = 384 float4.
  #pragma unroll
  for (int s = 0; s < 2; ++s) {
    const int q = tid + s * 256;
    if (q < 384) {
      const int row = q >> 5;
      const int col = q & 31;
      const int zz = (z + (row >> 2) - 1) & (HZ - 1);
      const int yy = (y0 + (row & 3) - 1) & (NN - 1);
      ((float4*)tile)[q] =
          *(const float4*)(anat + ((zz << 14) | (yy << 7) | (col << 2)));
    }
  }
  __syncthreads();

  const int xa[3] = {(x + NN - 1) & (NN - 1), x, (x + 1) & (NN - 1)};
  const float center = tile[512 + (yl + 1) * 128 + x];   // col 13

  // Pack keys: non-negative float bits are unsigned-order-isomorphic.
  unsigned long long key[NCOL];
  #pragma unroll
  for (int c = 0; c < NCOL; ++c) {
    const int zi = c / 9, yi = (c / 3) % 3;
    const float v = tile[zi * 512 + (yl + yi) * 128 + xa[c % 3]];
    const unsigned db = __float_as_uint(v - center) & 0x7fffffffu;
    key[c] = ((unsigned long long)db << 5) | (unsigned)c;
  }

  // Sorting network: 155 CEs, 5 VALU each.
  #pragma unroll
  for (int e = 0; e < NCE; ++e) {
    const int a = NET[e].a, b = NET[e].b;
    const unsigned long long xk = key[a], yk = key[b];
    const bool sw = xk > yk;
    key[a] = sw ? yk : xk;
    key[b] = sw ? xk : yk;
  }

  // Winners in rank order: re-read values by col, pack codes.
  float* myrow = &lrow[tid * ST];
  unsigned lo = 0, hi = 0;
  #pragma unroll
  for (int s = 0; s < KSEL; ++s) {
    const unsigned c = (unsigned)(key[s] & 31u);
    const unsigned czi = (c * 57u) >> 9;          // c / 9  (exact for c < 32)
    const unsigned rem = c - 9u * czi;
    const unsigned cyi = (rem * 11u) >> 5;        // rem / 3 (exact for rem < 9)
    const unsigned cxi = rem - 3u * cyi;
    myrow[s] = tile[czi * 512 + (yl + cyi) * 128 + xa[cxi]];
    if (s < 6) lo |= c << (5 * s);
    else       hi |= c << (5 * (s - 6));
  }
  myrow[9]  = __uint_as_float(lo);
  myrow[10] = __uint_as_float(hi);

  __syncthreads();

  // Coalesced writeback: 3 x 256 x float4 = 12 KB, full line coverage.
  float4* g = (float4*)(rows + (size_t)blockIdx.x * 256 * ST);
  const float4* l4 = (const float4*)lrow;
  #pragma unroll
  for (int rnd = 0; rnd < 3; ++rnd) g[rnd * 256 + tid] = l4[rnd * 256 + tid];
}

// ---------------------------------------------------------------------------
// Pass 2 (unchanged from R4): stage the 3z x 4y x 128x halo of rows (73.7 KB)
// into LDS with coalesced float4 loads; every gather is a conflict-free
// ds_read_b128; XCD swizzle keeps the 6x halo re-read L2-local.
// ---------------------------------------------------------------------------
__global__ __launch_bounds__(256) void weights4(
    const float* __restrict__ rows,
    const float* __restrict__ ksig,
    float* __restrict__ out) {
  __shared__ float tile[1536 * ST];   // 73728 B; reused for output staging
  const int tid = threadIdx.x;

  const int blk = blockIdx.x;
  const int swz = ((blk & 7) << 9) | (blk >> 3);

  const int ib = swz << 8;
  const int x  = tid & (NN - 1);
  const int yl = tid >> 7;
  const int y0 = (ib >> 7) & (NN - 1);
  const int z  = ib >> 14;

  const float4* rows4 = (const float4*)rows;
  float4* t4 = (float4*)tile;
  #pragma unroll
  for (int s = 0; s < 18; ++s) {
    const unsigned q = (unsigned)(s * 256 + tid);
    const unsigned p = q / 384u;          // (zi,yi) pair 0..11
    const unsigned f = q - p * 384u;
    const int zi = (int)(p >> 2), yi = (int)(p & 3u);
    const int zz = (z + zi - 1) & (HZ - 1);
    const int yy = (y0 + yi - 1) & (NN - 1);
    const int g0 = (zz << 14) | (yy << 7);
    t4[q] = rows4[(size_t)g0 * 3 + f];
  }
  __syncthreads();

  const int rho_own = 512 + (yl + 1) * 128 + x;
  const float4 w0 = t4[rho_own * 3], w1 = t4[rho_own * 3 + 1], w2 = t4[rho_own * 3 + 2];
  const float ws[KSEL] = {w0.x, w0.y, w0.z, w0.w, w1.x, w1.y, w1.z, w1.w, w2.x};
  const unsigned lo = __float_as_uint(w2.y);
  const unsigned hi = __float_as_uint(w2.z);

  float mean = 0.f;
  #pragma unroll
  for (int l = 0; l < KSEL; ++l) mean += ws[l];
  mean *= (1.0f / 9.0f);
  float var = 0.f;
  #pragma unroll
  for (int l = 0; l < KSEL; ++l) { const float t = ws[l] - mean; var += t * t; }
  var *= (1.0f / 8.0f);
  const float sigma = sqrtf(var);

  const float ks = ksig[0];
  const float inv = (sigma == 0.f) ? 0.f : 1.0f / (2.0f * ks * ks * sigma * sigma);

  float logit[KSEL];
  #pragma unroll
  for (int j = 0; j < KSEL; ++j) {
    const unsigned c = (j < 6) ? ((lo >> (5 * j)) & 31u)
                               : ((hi >> (5 * (j - 6))) & 31u);
    const unsigned czi = (c * 57u) >> 9;
    const unsigned rem = c - 9u * czi;
    const unsigned cyi = (rem * 11u) >> 5;
    const unsigned cxi = rem - 3u * cyi;
    const int rho = (int)czi * 512 + (yl + (int)cyi) * 128 + ((x + (int)cxi - 1) & (NN - 1));
    const float4 n0 = t4[rho * 3], n1 = t4[rho * 3 + 1], n2 = t4[rho * 3 + 2];
    const float nv[KSEL] = {n0.x, n0.y, n0.z, n0.w, n1.x, n1.y, n1.z, n1.w, n2.x};
    float s = 0.f;
    #pragma unroll
    for (int l = 0; l < KSEL; ++l) {
      const float t = ws[l] - nv[l] + 1e-6f;
      s = fmaf(t, t, s);
    }
    logit[j] = -s * inv;
  }

  float mx = logit[0];
  #pragma unroll
  for (int j = 1; j < KSEL; ++j) mx = fmaxf(mx, logit[j]);
  float sum = 0.f;
  float e[KSEL];
  #pragma unroll
  for (int j = 0; j < KSEL; ++j) { e[j] = __expf(logit[j] - mx); sum += e[j]; }
  const float rs = 1.0f / sum;

  __syncthreads();
  #pragma unroll
  for (int j = 0; j < KSEL; ++j) tile[tid * KSEL + j] = e[j] * rs;
  __syncthreads();

  float4* g = (float4*)(out + (size_t)swz * (256 * KSEL));
  g[tid]       = t4[tid];
  g[256 + tid] = t4[256 + tid];
  if (tid < 64) g[512 + tid] = t4[512 + tid];
}

// ---------------------------------------------------------------------------
// d_in: [0] input (P floats), [1] ksigma (1 float), [2] k (int), [3] w (int)
// d_ws: row array, P * 12 floats = 48 MB
// ---------------------------------------------------------------------------
extern "C" void kernel_launch(void* const* d_in, const int* in_sizes, int n_in,
                              void* d_out, int out_size, void* d_ws, size_t ws_size,
                              hipStream_t stream) {
  const float* anat = (const float*)d_in[0];
  const float* ksig = (const float*)d_in[1];
  float* rows = (float*)d_ws;

  const int blocks = P / 256;
  topk4<<<blocks, 256, 0, stream>>>(anat, rows);
  weights4<<<blocks, 256, 0, stream>>>(rows, ksig, (float*)d_out);
}